// Round 1
// 270.307 us; speedup vs baseline: 1.0112x; 1.0112x over previous
//
#include <hip/hip_runtime.h>
#include <cfloat>
#include <cmath>

// Constants fixed by setup_inputs: n=4, L=1024, d=768, h=12, E=32, M=4, R=256
#define N_ 4
#define L_ 1024
#define D_ 768
#define H_ 12
#define E_ 32
#define M_ 4
#define R_ 256

// Inputs & output FP32 (confirmed R1: k3 WRITE_SIZE == N*R*D*4B).
// Intermediates seqT / e_att / ht are bf16 (feed MFMA); e_emb fp32 (hs/ts exact).
typedef __attribute__((ext_vector_type(8))) short bf16x8;   // MFMA A/B frag
typedef __attribute__((ext_vector_type(4))) float f32x4;    // MFMA C/D frag

__device__ __forceinline__ ushort f2bf(float f) {
    unsigned u = __float_as_uint(f);
    return (ushort)((u + 0x7fffu + ((u >> 16) & 1u)) >> 16);   // RNE
}
__device__ __forceinline__ float bf2f(ushort u) { return __uint_as_float(((unsigned)u) << 16); }

// ---------------- k01: fused (independent) transpose-role + entity-role ------------------
// blocks [0,768): seqT[doc][d][l] = bf16(seq[doc][l][d]), 64x64 swizzled-LDS tile
// blocks [768, 768+1536): per (doc,entity,head) e_att (bf16); head==0 lanes also e_emb lse
__global__ __launch_bounds__(256) void k01(const float* __restrict__ seq,
                                           const float* __restrict__ att,
                                           const int* __restrict__ mpos,
                                           const float* __restrict__ mmask,
                                           ushort* __restrict__ seqT,
                                           float* __restrict__ e_emb,
                                           ushort* __restrict__ e_att) {
    const int b = blockIdx.x;
    const int t = threadIdx.x;                 // 256
    __shared__ ushort tile[64 * 64];           // 8 KB (transpose role); entity uses 16 B

    if (b < 768) {
        // ---- transpose role: grid factors 16(l-tile) x 12(d-tile) x 4(doc)
        const int lt = b & 15, dt = (b >> 4) % 12, doc = b / 192;
        const int l0 = lt * 64, d0 = dt * 64;
        #pragma unroll
        for (int i = 0; i < 2; i++) {
            int idx = t + i * 256;             // 0..511
            int row = idx >> 3;                // l-local
            int c8  = (idx & 7) << 3;          // d-local chunk start
            const float* src = seq + ((size_t)doc * L_ + (l0 + row)) * D_ + d0 + c8;
            float4 v0 = *(const float4*)(src);
            float4 v1 = *(const float4*)(src + 4);
            ushort tmp[8] = { f2bf(v0.x), f2bf(v0.y), f2bf(v0.z), f2bf(v0.w),
                              f2bf(v1.x), f2bf(v1.y), f2bf(v1.z), f2bf(v1.w) };
            int slot = (c8 + (row & 56)) & 63; // swizzle; chunk never wraps
            *(uint4*)(tile + row * 64 + slot) = *(const uint4*)tmp;
        }
        __syncthreads();
        #pragma unroll
        for (int i = 0; i < 2; i++) {
            int idx = t + i * 256;
            int drow = idx >> 3;               // d-local
            int l8 = (idx & 7) << 3;           // l-local chunk
            int slot = (drow + l8) & 63;
            ushort tmp[8];
            #pragma unroll
            for (int j = 0; j < 8; j++) tmp[j] = tile[(l8 + j) * 64 + slot];
            *(uint4*)(seqT + ((size_t)doc * D_ + (d0 + drow)) * L_ + l0 + l8) = *(const uint4*)tmp;
        }
        return;
    }

    // ---- entity role: b2 in [0,1536) = be*H + head
    const int b2 = b - 768;
    const int head = b2 % H_;
    const int be = b2 / H_;                    // doc*E + e
    const int doc = be >> 5;

    __shared__ int   spos[M_];
    __shared__ float smask[M_];
    if (t < M_) {
        spos[t]  = mpos[be * M_ + t] + 1;      // OFFSET
        smask[t] = mmask[be * M_ + t];
    }
    __syncthreads();
    const float cnt = fmaxf(smask[0] + smask[1] + smask[2] + smask[3], 1.0f);
    const float inv_cnt = 1.0f / cnt;

    // e_att: all 256 threads, 4 floats each (float4, 16B/lane perfectly coalesced)
    {
        const int l4 = t << 2;
        float s0 = 0, s1 = 0, s2 = 0, s3 = 0;
        #pragma unroll
        for (int m = 0; m < M_; m++) {
            float4 r = *(const float4*)(att + (((size_t)doc * H_ + head) * L_ + spos[m]) * L_ + l4);
            const float w = smask[m];
            s0 += w * r.x; s1 += w * r.y; s2 += w * r.z; s3 += w * r.w;
        }
        ushort o[4] = { f2bf(s0 * inv_cnt), f2bf(s1 * inv_cnt),
                        f2bf(s2 * inv_cnt), f2bf(s3 * inv_cnt) };
        *(uint2*)(e_att + ((size_t)be * H_ + head) * L_ + l4) = *(const uint2*)o;
    }

    // e_emb lse (fp32), once per entity, concurrent with e_att above
    if (head == 0 && t < 96) {
        const int j8 = t << 3;
        float v[M_][8];
        #pragma unroll
        for (int m = 0; m < M_; m++) {
            const float* src = seq + ((size_t)doc * L_ + spos[m]) * D_ + j8;
            float4 r0 = *(const float4*)(src);
            float4 r1 = *(const float4*)(src + 4);
            v[m][0] = r0.x; v[m][1] = r0.y; v[m][2] = r0.z; v[m][3] = r0.w;
            v[m][4] = r1.x; v[m][5] = r1.y; v[m][6] = r1.z; v[m][7] = r1.w;
        }
        float o[8];
        #pragma unroll
        for (int j = 0; j < 8; j++) {
            float x[M_];
            #pragma unroll
            for (int m = 0; m < M_; m++) x[m] = (smask[m] > 0.0f) ? v[m][j] : -FLT_MAX;
            float mx = fmaxf(fmaxf(x[0], x[1]), fmaxf(x[2], x[3]));
            float s = 0.0f;
            #pragma unroll
            for (int m = 0; m < M_; m++) s += expf(x[m] - mx);
            o[j] = mx + logf(s);
        }
        float* dst = e_emb + (size_t)be * D_ + j8;
        *(float4*)(dst)     = make_float4(o[0], o[1], o[2], o[3]);
        *(float4*)(dst + 4) = make_float4(o[4], o[5], o[6], o[7]);
    }
}

// ---------------- k2: per pair: hs/ts (fp32 copies), ht_att (normalized bf16) ------------
__global__ __launch_bounds__(256) void k2_pairs(const int* __restrict__ hts,
                                                const float* __restrict__ e_emb,
                                                const ushort* __restrict__ e_att,
                                                ushort* __restrict__ ht_att,
                                                float* __restrict__ out) {
    const int b = blockIdx.x;                  // doc*R + r
    const int doc = b >> 8;
    const int t = threadIdx.x;                 // 256
    const int hi = hts[b * 2 + 0];
    const int ti = hts[b * 2 + 1];

    if (t < 192) {                             // hs / ts: exact fp32 copies (never re-read -> nt stores)
        const int j4 = t << 2;
        f32x4 hv = *(const f32x4*)(e_emb + (size_t)(doc * E_ + hi) * D_ + j4);
        f32x4 tv = *(const f32x4*)(e_emb + (size_t)(doc * E_ + ti) * D_ + j4);
        __builtin_nontemporal_store(hv, (f32x4*)(out + (size_t)b * D_ + j4));
        __builtin_nontemporal_store(tv, (f32x4*)(out + (size_t)N_ * R_ * D_ + (size_t)b * D_ + j4));
    }

    const ushort* ha = e_att + (size_t)(doc * E_ + hi) * H_ * L_;
    const ushort* ta = e_att + (size_t)(doc * E_ + ti) * H_ * L_;
    const int l4 = t << 2;
    float s[4] = {0, 0, 0, 0};
    #pragma unroll
    for (int head = 0; head < H_; head++) {
        union { uint2 v; ushort u[4]; } x, y;
        x.v = *(const uint2*)(ha + head * L_ + l4);
        y.v = *(const uint2*)(ta + head * L_ + l4);
        #pragma unroll
        for (int j = 0; j < 4; j++) s[j] += bf2f(x.u[j]) * bf2f(y.u[j]);
    }
    #pragma unroll
    for (int j = 0; j < 4; j++) s[j] *= (1.0f / H_);
    float p = s[0] + s[1] + s[2] + s[3];
    #pragma unroll
    for (int off = 32; off > 0; off >>= 1) p += __shfl_down(p, off, 64);
    __shared__ float swave[4];
    if ((t & 63) == 0) swave[t >> 6] = p;
    __syncthreads();
    const float total = swave[0] + swave[1] + swave[2] + swave[3];
    const float norm = 1.0f / (total + 1e-5f);
    ushort o[4];
    #pragma unroll
    for (int j = 0; j < 4; j++) o[j] = f2bf(s[j] * norm);
    *(uint2*)(ht_att + (size_t)b * L_ + l4) = *(const uint2*)o;
}

// ---------------- k3: rs via MFMA: D[d][r] = sum_l seqT[d][l] * ht[r][l] -----------------
// 1 wave/block -> latency-bound on L2 loads; 2-step-deep software pipeline (distance-2
// prefetch, named regs so everything stays in VGPRs) to cover ~200-300cy L2 latency.
__global__ void k3_rs(const ushort* __restrict__ seqT, const ushort* __restrict__ ht,
                      float* __restrict__ out_rs) {
    const int doc = blockIdx.z;
    const int d0 = blockIdx.x * 32;
    const int r0 = blockIdx.y * 32;
    const int lane = threadIdx.x;              // 64
    const int l15 = lane & 15;
    const int quad = lane >> 4;

    const ushort* Ab = seqT + ((size_t)doc * D_ + d0 + l15) * L_ + quad * 8;
    const ushort* Bb = ht   + ((size_t)doc * R_ + r0 + l15) * L_ + quad * 8;

    // even regs hold step k, odd regs hold step k+32
    bf16x8 eA0 = *(const bf16x8*)(Ab);
    bf16x8 eA1 = *(const bf16x8*)(Ab + 16 * L_);
    bf16x8 eB0 = *(const bf16x8*)(Bb);
    bf16x8 eB1 = *(const bf16x8*)(Bb + 16 * L_);
    bf16x8 oA0 = *(const bf16x8*)(Ab + 32);
    bf16x8 oA1 = *(const bf16x8*)(Ab + 32 + 16 * L_);
    bf16x8 oB0 = *(const bf16x8*)(Bb + 32);
    bf16x8 oB1 = *(const bf16x8*)(Bb + 32 + 16 * L_);
    f32x4 c00 = {0, 0, 0, 0}, c01 = {0, 0, 0, 0}, c10 = {0, 0, 0, 0}, c11 = {0, 0, 0, 0};

    for (int k = 0; k < L_; k += 64) {
        // ---- even step (k): prefetch k+64 (distance 2), then consume step-k regs
        bf16x8 nA0 = eA0, nA1 = eA1, nB0 = eB0, nB1 = eB1;
        if (k + 64 < L_) {
            nA0 = *(const bf16x8*)(Ab + k + 64);
            nA1 = *(const bf16x8*)(Ab + k + 64 + 16 * L_);
            nB0 = *(const bf16x8*)(Bb + k + 64);
            nB1 = *(const bf16x8*)(Bb + k + 64 + 16 * L_);
        }
        c00 = __builtin_amdgcn_mfma_f32_16x16x32_bf16(eA0, eB0, c00, 0, 0, 0);
        c01 = __builtin_amdgcn_mfma_f32_16x16x32_bf16(eA0, eB1, c01, 0, 0, 0);
        c10 = __builtin_amdgcn_mfma_f32_16x16x32_bf16(eA1, eB0, c10, 0, 0, 0);
        c11 = __builtin_amdgcn_mfma_f32_16x16x32_bf16(eA1, eB1, c11, 0, 0, 0);
        eA0 = nA0; eA1 = nA1; eB0 = nB0; eB1 = nB1;

        // ---- odd step (k+32): prefetch k+96, then consume step-(k+32) regs
        bf16x8 mA0 = oA0, mA1 = oA1, mB0 = oB0, mB1 = oB1;
        if (k + 96 < L_) {
            mA0 = *(const bf16x8*)(Ab + k + 96);
            mA1 = *(const bf16x8*)(Ab + k + 96 + 16 * L_);
            mB0 = *(const bf16x8*)(Bb + k + 96);
            mB1 = *(const bf16x8*)(Bb + k + 96 + 16 * L_);
        }
        c00 = __builtin_amdgcn_mfma_f32_16x16x32_bf16(oA0, oB0, c00, 0, 0, 0);
        c01 = __builtin_amdgcn_mfma_f32_16x16x32_bf16(oA0, oB1, c01, 0, 0, 0);
        c10 = __builtin_amdgcn_mfma_f32_16x16x32_bf16(oA1, oB0, c10, 0, 0, 0);
        c11 = __builtin_amdgcn_mfma_f32_16x16x32_bf16(oA1, oB1, c11, 0, 0, 0);
        oA0 = mA0; oA1 = mA1; oB0 = mB0; oB1 = mB1;
    }

    // C/D layout: col(=r) = lane&15, row(=d) = quad*4 + reg. Output never re-read -> nt stores.
    f32x4 cc[2][2] = {{c00, c01}, {c10, c11}};
    #pragma unroll
    for (int di = 0; di < 2; di++) {
        #pragma unroll
        for (int ri = 0; ri < 2; ri++) {
            const int r = r0 + ri * 16 + l15;
            const int d = d0 + di * 16 + quad * 4;
            __builtin_nontemporal_store(cc[di][ri],
                (f32x4*)(out_rs + ((size_t)doc * R_ + r) * D_ + d));
        }
    }
}

extern "C" void kernel_launch(void* const* d_in, const int* in_sizes, int n_in,
                              void* d_out, int out_size, void* d_ws, size_t ws_size,
                              hipStream_t stream) {
    const float* seq   = (const float*)d_in[0];   // (n,L,d) fp32
    const float* att   = (const float*)d_in[1];   // (n,h,L,L) fp32
    const int*   mpos  = (const int*)d_in[2];     // (n,E,M) int32
    const float* mmask = (const float*)d_in[3];   // (n,E,M) fp32
    const int*   hts   = (const int*)d_in[4];     // (n,R,2) int32
    float* out = (float*)d_out;                   // 3*(n*R)*d fp32

    float*  e_emb = (float*)d_ws;                                    // n*E*D fp32
    ushort* seqT  = (ushort*)(e_emb + (size_t)N_ * E_ * D_);         // n*D*L bf16
    ushort* e_att = seqT  + (size_t)N_ * D_ * L_;                    // n*E*H*L bf16
    ushort* ht    = e_att + (size_t)N_ * E_ * H_ * L_;               // n*R*L bf16

    k01<<<768 + N_ * E_ * H_, 256, 0, stream>>>(seq, att, mpos, mmask, seqT, e_emb, e_att);
    k2_pairs<<<N_ * R_, 256, 0, stream>>>(hts, e_emb, e_att, ht, out);
    dim3 g3(D_ / 32, R_ / 32, N_);
    k3_rs<<<g3, 64, 0, stream>>>(seqT, ht, out + (size_t)2 * N_ * R_ * D_);
}